// Round 1
// 1073.607 us; speedup vs baseline: 1.1023x; 1.1023x over previous
//
#include <hip/hip_runtime.h>
#include <hip/hip_fp16.h>
#include <stdint.h>

#define VOCAB 32000
#define EMB   256
#define HID   512
#define BATCH 64
#define SEQ   512

// ---------------------------------------------------------------------------
// fp16 dot2: v_dot2_f32_f16 (2 MACs/lane/instr, fp32 accumulate)
// ---------------------------------------------------------------------------
typedef _Float16 h2_t __attribute__((ext_vector_type(2)));

__device__ __forceinline__ float fdot2(unsigned int a, unsigned int b, float c) {
#if __has_builtin(__builtin_amdgcn_fdot2)
    return __builtin_amdgcn_fdot2(__builtin_bit_cast(h2_t, a),
                                  __builtin_bit_cast(h2_t, b), c, false);
#else
    __half2 ah = __builtin_bit_cast(__half2, a);
    __half2 bh = __builtin_bit_cast(__half2, b);
    float2 af = __half22float2(ah), bf = __half22float2(bh);
    return fmaf(af.y, bf.y, fmaf(af.x, bf.x, c));
#endif
}

// DPP quad_perm lane-swap + add (pure VALU cross-lane within a hw quad)
template<int CTRL>
__device__ __forceinline__ float quad_add(float x) {
    int v = __builtin_amdgcn_update_dpp(0, __builtin_bit_cast(int, x),
                                        CTRL, 0xF, 0xF, true);
    return x + __builtin_bit_cast(float, v);
}
__device__ __forceinline__ float quad_reduce(float x) {
    x = quad_add<0xB1>(x);   // quad_perm [1,0,3,2] : xor 1
    x = quad_add<0x4E>(x);   // quad_perm [2,3,0,1] : xor 2
    return x;
}

// ---------------------------------------------------------------------------
// Kernel 1: pack W_hh (fp32 [r][k]) -> fp16 pairs, Wpk[j][r], j = k/2
// ---------------------------------------------------------------------------
__global__ void prep_whh(const float* __restrict__ W_hh, unsigned int* __restrict__ Wpk) {
    int idx = blockIdx.x * blockDim.x + threadIdx.x;      // = j*HID + r
    if (idx >= HID * (HID / 2)) return;
    int r = idx & (HID - 1);
    int j = idx >> 9;
    float lo = W_hh[r * HID + 2 * j];
    float hi = W_hh[r * HID + 2 * j + 1];
    unsigned int u = ((unsigned int)__half_as_ushort(__float2half(hi)) << 16)
                   |  (unsigned int)__half_as_ushort(__float2half(lo));
    Wpk[idx] = u;
}

// ---------------------------------------------------------------------------
// Kernel 2: xin[b][s][h] = emb[X[b][s]] . W_ih[h] + b_ih[h] + b_hh[h]  (fp16 out)
// 128x128 tile, BK=32, 256 thr, 8x8 acc/thread (split 4+4 to keep LDS 2-way free)
// ---------------------------------------------------------------------------
#define TSA 132

__global__ __launch_bounds__(256) void embed_gemm(
    const int* __restrict__ X, const float* __restrict__ emb,
    const float* __restrict__ W_ih, const float* __restrict__ b_ih,
    const float* __restrict__ b_hh, __half* __restrict__ xin) {
    __shared__ float A_l[32 * TSA];
    __shared__ float B_l[32 * TSA];
    const int tid = threadIdx.x;
    const int tx = tid & 15, ty = tid >> 4;
    const int sb0 = blockIdx.x * 128;   // (b*S+s) row tile
    const int h0  = blockIdx.y * 128;   // hidden col tile

    float acc[8][8] = {};   // rows {ty*4+i, 64+ty*4+i} x cols {tx*4+j, 64+tx*4+j}

    for (int kc = 0; kc < EMB; kc += 32) {
#pragma unroll
        for (int q = 0; q < 4; ++q) {
            int idx = q * 256 + tid;
            int r  = idx >> 3;          // 0..127
            int c4 = idx & 7;           // 0..7 float4 along k
            int row = X[sb0 + r];
            float4 v = *(const float4*)(emb + (size_t)row * EMB + kc + c4 * 4);
            A_l[(c4 * 4 + 0) * TSA + r] = v.x;
            A_l[(c4 * 4 + 1) * TSA + r] = v.y;
            A_l[(c4 * 4 + 2) * TSA + r] = v.z;
            A_l[(c4 * 4 + 3) * TSA + r] = v.w;
        }
#pragma unroll
        for (int q = 0; q < 4; ++q) {
            int idx = q * 256 + tid;
            int r  = idx >> 3;
            int c4 = idx & 7;
            float4 v = *(const float4*)(W_ih + (size_t)(h0 + r) * EMB + kc + c4 * 4);
            B_l[(c4 * 4 + 0) * TSA + r] = v.x;
            B_l[(c4 * 4 + 1) * TSA + r] = v.y;
            B_l[(c4 * 4 + 2) * TSA + r] = v.z;
            B_l[(c4 * 4 + 3) * TSA + r] = v.w;
        }
        __syncthreads();
#pragma unroll
        for (int k = 0; k < 32; ++k) {
            float4 a0 = *(const float4*)&A_l[k * TSA + ty * 4];
            float4 a1 = *(const float4*)&A_l[k * TSA + 64 + ty * 4];
            float4 b0 = *(const float4*)&B_l[k * TSA + tx * 4];
            float4 b1 = *(const float4*)&B_l[k * TSA + 64 + tx * 4];
            float ar[8] = {a0.x, a0.y, a0.z, a0.w, a1.x, a1.y, a1.z, a1.w};
            float br[8] = {b0.x, b0.y, b0.z, b0.w, b1.x, b1.y, b1.z, b1.w};
#pragma unroll
            for (int i = 0; i < 8; ++i)
#pragma unroll
                for (int j = 0; j < 8; ++j)
                    acc[i][j] = fmaf(ar[i], br[j], acc[i][j]);
        }
        __syncthreads();
    }

    float bias[8];
#pragma unroll
    for (int j = 0; j < 8; ++j) {
        int h = h0 + (j < 4 ? tx * 4 + j : 64 + tx * 4 + (j - 4));
        bias[j] = b_ih[h] + b_hh[h];
    }
#pragma unroll
    for (int i = 0; i < 8; ++i) {
        int r = sb0 + (i < 4 ? ty * 4 + i : 64 + ty * 4 + (i - 4));
        __half* dst = xin + (size_t)r * HID + h0;
        __half2 v01 = __floats2half2_rn(acc[i][0] + bias[0], acc[i][1] + bias[1]);
        __half2 v23 = __floats2half2_rn(acc[i][2] + bias[2], acc[i][3] + bias[3]);
        __half2 v45 = __floats2half2_rn(acc[i][4] + bias[4], acc[i][5] + bias[5]);
        __half2 v67 = __floats2half2_rn(acc[i][6] + bias[6], acc[i][7] + bias[7]);
        *(__half2*)(dst + tx * 4)          = v01;
        *(__half2*)(dst + tx * 4 + 2)      = v23;
        *(__half2*)(dst + 64 + tx * 4)     = v45;
        *(__half2*)(dst + 64 + tx * 4 + 2) = v67;
    }
}

// ---------------------------------------------------------------------------
// Kernel 3: sequential RNN scan, one 512-thread block per batch chain.
// Thread t (p=t>>2, g=t&3) owns rows {p+128i} over k-quarter g:
//   4 rows x 56 pairs in VGPRs (224) + 4 x 8 tail pairs in LDS (b128-readable).
// REGISTER BUDGET: grid is 64 blocks -> 1 block/CU, so the only effect of the
// launch-bounds occupancy hint is the VGPR cap. (512,2) capped at 128 VGPRs and
// spilled the 224-dword weight array to scratch, reloaded every step (measured
// VGPR_Count=128). (512,1) allows ~256; demand is ~250 -> no structural spill.
// wt stride 36 dwords (== +4 mod 32): consecutive 8 lanes' b128 reads tile all
// 32 banks exactly once -> conflict-free (same property as old stride 28).
// h kept fp16 in LDS, double-buffered, quarters padded 16B (bank-disjoint
// 4-address multicast). DPP quad reduction -> 1 barrier/step.
// xin fp16 is overwritten in place with h (prefetch-before-write, thread-private).
// ---------------------------------------------------------------------------
#define QSTRIDE 272            // bytes per padded h quarter (256 data + 16 pad)
#define HBUF_DW 272            // dwords per h buffer = 4*272/4
#define NREG    56             // weight pairs per row kept in VGPRs
#define NTAIL   8              // weight pairs per row kept in LDS
#define WT_STR  36             // dwords per thread in wt (8 pairs x 4 rows + 4 pad)

__global__ __launch_bounds__(512, 1) void rnn_scan(
    __half* __restrict__ buf,                     // [B][S][HID] fp16: xin in, h out
    const unsigned int* __restrict__ Wpk) {
    __shared__ unsigned int wt[WT_STR * 512];     // wt[t*WT_STR + k*4 + i]
    __shared__ unsigned int hbuf[2 * HBUF_DW];    // 2 x (4 padded quarters)

    const int t = threadIdx.x;
    const int b = blockIdx.x;
    const int g = t & 3;
    const int p = t >> 2;

    unsigned int wreg[4 * NREG];
#pragma unroll
    for (int i = 0; i < 4; ++i)
#pragma unroll
        for (int off = 0; off < NREG; ++off)
            wreg[i * NREG + off] = Wpk[(g * 64 + off) * HID + p + 128 * i];
#pragma unroll
    for (int k = 0; k < NTAIL; ++k)
#pragma unroll
        for (int i = 0; i < 4; ++i)
            wt[t * WT_STR + k * 4 + i] = Wpk[(g * 64 + NREG + k) * HID + p + 128 * i];
    for (int i = t; i < 2 * HBUF_DW; i += 512) hbuf[i] = 0;
    __syncthreads();

    const int rf = p + 128 * g;                   // row this thread finalizes
    const __half* xp = buf + (size_t)b * SEQ * HID + rf;
    __half* op = buf + (size_t)b * SEQ * HID + rf;
    const uint4* wt4 = (const uint4*)&wt[t * WT_STR];

    float xcur = __half2float(xp[0]);
    __half hprev = __float2half(0.0f);

    for (int s = 0; s < SEQ; ++s) {
        if (s > 0) op[(size_t)(s - 1) * HID] = hprev;     // last step's h, early
        float xnext = 0.0f;
        if (s + 1 < SEQ) xnext = __half2float(xp[(size_t)(s + 1) * HID]);

        const uint4* hq = (const uint4*)((const char*)hbuf
                              + (s & 1) * (HBUF_DW * 4) + g * QSTRIDE);
        float acc[4] = {0.f, 0.f, 0.f, 0.f};
#pragma unroll
        for (int q = 0; q < 14; ++q) {            // pairs 0..55 from VGPR weights
            uint4 h4 = hq[q];
#pragma unroll
            for (int i = 0; i < 4; ++i) {
                const unsigned int* wi = &wreg[i * NREG + 4 * q];
                acc[i] = fdot2(wi[0], h4.x, acc[i]);
                acc[i] = fdot2(wi[1], h4.y, acc[i]);
                acc[i] = fdot2(wi[2], h4.z, acc[i]);
                acc[i] = fdot2(wi[3], h4.w, acc[i]);
            }
        }
        {   // tail: pairs 56..63 from LDS (per-thread-contiguous b128, stride 36)
            uint4 h14 = hq[14];
            uint4 h15 = hq[15];
            unsigned int hc[NTAIL] = {h14.x, h14.y, h14.z, h14.w,
                                      h15.x, h15.y, h15.z, h15.w};
#pragma unroll
            for (int k = 0; k < NTAIL; ++k) {
                uint4 w = wt4[k];
                acc[0] = fdot2(w.x, hc[k], acc[0]);
                acc[1] = fdot2(w.y, hc[k], acc[1]);
                acc[2] = fdot2(w.z, hc[k], acc[2]);
                acc[3] = fdot2(w.w, hc[k], acc[3]);
            }
        }
        // reduce each row-partial over the quad (pure VALU), pick own row
        acc[0] = quad_reduce(acc[0]);
        acc[1] = quad_reduce(acc[1]);
        acc[2] = quad_reduce(acc[2]);
        acc[3] = quad_reduce(acc[3]);
        float dot = (g & 2) ? ((g & 1) ? acc[3] : acc[2])
                            : ((g & 1) ? acc[1] : acc[0]);
        float z = xcur + dot;
        float e = __expf(2.0f * z);                // tanh via exp, saturates right
        float hn = 1.0f - 2.0f / (e + 1.0f);
        __half hh = __float2half(hn);
        *((__half*)((char*)hbuf + ((s + 1) & 1) * (HBUF_DW * 4) + g * QSTRIDE) + p) = hh;
        hprev = hh;
        xcur = xnext;
        __syncthreads();                           // single barrier per step
    }
    op[(size_t)(SEQ - 1) * HID] = hprev;
}

// ---------------------------------------------------------------------------
// Kernel 4: attention over trajectory + feat assembly. One block per batch.
// ---------------------------------------------------------------------------
__global__ __launch_bounds__(256) void attn_ctx(
    const __half* __restrict__ h_all, float* __restrict__ feat) {
    const int b = blockIdx.x, tid = threadIdx.x;
    __shared__ float lastv[HID];
    __shared__ float sc[SEQ];
    __shared__ float red[256];
    const __half* hb = h_all + (size_t)b * SEQ * HID;

    for (int i = tid; i < HID; i += 256)
        lastv[i] = __half2float(hb[(size_t)(SEQ - 1) * HID + i]);
    __syncthreads();

    for (int s = tid; s < SEQ - 1; s += 256) {
        const __half* row = hb + (size_t)s * HID;
        float acc = 0.f;
        for (int r = 0; r < HID; r += 2) {
            __half2 hv = *(const __half2*)(row + r);
            float2 f = __half22float2(hv);
            acc = fmaf(f.x, lastv[r], acc);
            acc = fmaf(f.y, lastv[r + 1], acc);
        }
        sc[s] = acc;
    }
    __syncthreads();

    float m = -1e30f;
    for (int s = tid; s < SEQ - 1; s += 256) m = fmaxf(m, sc[s]);
    red[tid] = m;
    __syncthreads();
    for (int o = 128; o > 0; o >>= 1) {
        if (tid < o) red[tid] = fmaxf(red[tid], red[tid + o]);
        __syncthreads();
    }
    m = red[0];
    __syncthreads();

    float psum = 0.f;
    for (int s = tid; s < SEQ - 1; s += 256) {
        float e = expf(sc[s] - m);
        sc[s] = e;
        psum += e;
    }
    red[tid] = psum;
    __syncthreads();
    for (int o = 128; o > 0; o >>= 1) {
        if (tid < o) red[tid] += red[tid + o];
        __syncthreads();
    }
    float inv = 1.0f / red[0];
    __syncthreads();

    // ctx: each thread owns 2 adjacent r via half2, s-loop unrolled x4
    for (int r2 = tid; r2 < HID / 2; r2 += 256) {
        int r = r2 * 2;
        float accx = 0.f, accy = 0.f;
        int s = 0;
        for (; s + 4 <= SEQ - 1; s += 4) {
#pragma unroll
            for (int u = 0; u < 4; ++u) {
                __half2 hv = *(const __half2*)(hb + (size_t)(s + u) * HID + r);
                float2 f = __half22float2(hv);
                float w = sc[s + u];
                accx = fmaf(w, f.x, accx);
                accy = fmaf(w, f.y, accy);
            }
        }
        for (; s < SEQ - 1; ++s) {
            __half2 hv = *(const __half2*)(hb + (size_t)s * HID + r);
            float2 f = __half22float2(hv);
            float w = sc[s];
            accx = fmaf(w, f.x, accx);
            accy = fmaf(w, f.y, accy);
        }
        feat[(size_t)b * 2 * HID + r]     = accx * inv;
        feat[(size_t)b * 2 * HID + r + 1] = accy * inv;
        feat[(size_t)b * 2 * HID + HID + r]     = lastv[r];
        feat[(size_t)b * 2 * HID + HID + r + 1] = lastv[r + 1];
    }
}

// ---------------------------------------------------------------------------
// Kernel 5: out[b][v] = feat[b] . W[v] + bias[v].  64 v-rows x 64 b per block.
// ---------------------------------------------------------------------------
#define TS 68

__global__ __launch_bounds__(256) void final_gemm(
    const float* __restrict__ W, const float* __restrict__ bias,
    const float* __restrict__ feat, float* __restrict__ out) {
    __shared__ float A_l[64 * TS];   // W tile, k-major
    __shared__ float B_l[64 * TS];   // feat tile, k-major
    const int tid = threadIdx.x;
    const int tx = tid & 15, ty = tid >> 4;
    const int v0 = blockIdx.x * 64;

    float acc[4][4] = {};            // [v-row i][b-col ii]

    for (int kc = 0; kc < 2 * HID; kc += 64) {
#pragma unroll
        for (int q = 0; q < 4; ++q) {
            int idx = q * 256 + tid;
            int r  = idx >> 4;
            int c4 = idx & 15;
            const float4 v = *(const float4*)(W + (size_t)(v0 + r) * (2 * HID) + kc + c4 * 4);
            A_l[(c4 * 4 + 0) * TS + r] = v.x;
            A_l[(c4 * 4 + 1) * TS + r] = v.y;
            A_l[(c4 * 4 + 2) * TS + r] = v.z;
            A_l[(c4 * 4 + 3) * TS + r] = v.w;
        }
#pragma unroll
        for (int q = 0; q < 4; ++q) {
            int idx = q * 256 + tid;
            int r  = idx >> 4;       // batch row 0..63
            int c4 = idx & 15;
            const float4 v = *(const float4*)(feat + (size_t)r * (2 * HID) + kc + c4 * 4);
            B_l[(c4 * 4 + 0) * TS + r] = v.x;
            B_l[(c4 * 4 + 1) * TS + r] = v.y;
            B_l[(c4 * 4 + 2) * TS + r] = v.z;
            B_l[(c4 * 4 + 3) * TS + r] = v.w;
        }
        __syncthreads();
#pragma unroll 8
        for (int k = 0; k < 64; ++k) {
            float4 av = *(const float4*)&A_l[k * TS + ty * 4];
            float4 bv = *(const float4*)&B_l[k * TS + tx * 4];
            float a[4] = {av.x, av.y, av.z, av.w};
            float bb[4] = {bv.x, bv.y, bv.z, bv.w};
#pragma unroll
            for (int i = 0; i < 4; ++i)
#pragma unroll
                for (int ii = 0; ii < 4; ++ii)
                    acc[i][ii] = fmaf(a[i], bb[ii], acc[i][ii]);
        }
        __syncthreads();
    }

    float bs[4];
#pragma unroll
    for (int i = 0; i < 4; ++i) bs[i] = bias[v0 + ty * 4 + i];
#pragma unroll
    for (int ii = 0; ii < 4; ++ii) {
        int bb = tx * 4 + ii;
        float4 o;
        o.x = acc[0][ii] + bs[0];
        o.y = acc[1][ii] + bs[1];
        o.z = acc[2][ii] + bs[2];
        o.w = acc[3][ii] + bs[3];
        *(float4*)(out + (size_t)bb * VOCAB + v0 + ty * 4) = o;
    }
}

// ---------------------------------------------------------------------------
extern "C" void kernel_launch(void* const* d_in, const int* in_sizes, int n_in,
                              void* d_out, int out_size, void* d_ws, size_t ws_size,
                              hipStream_t stream) {
    const int*   X    = (const int*)d_in[0];
    const float* emb  = (const float*)d_in[1];
    const float* W_ih = (const float*)d_in[2];
    const float* W_hh = (const float*)d_in[3];
    const float* b_ih = (const float*)d_in[4];
    const float* b_hh = (const float*)d_in[5];
    const float* W    = (const float*)d_in[6];
    const float* bias = (const float*)d_in[7];
    float* out = (float*)d_out;

    // workspace: buf (xin fp16, overlaid with h) 32 MB | Wpk 512 KB | feat 256 KB
    const size_t BUF_B  = (size_t)BATCH * SEQ * HID * sizeof(__half);  // 33554432
    const size_t WPK_B  = (size_t)(HID * HID / 2) * sizeof(unsigned);  //   524288
    const size_t FEAT_B = (size_t)BATCH * 2 * HID * sizeof(float);     //   262144
    if (ws_size < BUF_B + WPK_B + FEAT_B) return;  // fail clean, don't corrupt

    char* ws = (char*)d_ws;
    __half*       buf  = (__half*)ws;
    unsigned int* Wpk  = (unsigned int*)(ws + BUF_B);
    float*        feat = (float*)(ws + BUF_B + WPK_B);

    prep_whh<<<(HID * HID / 2 + 255) / 256, 256, 0, stream>>>(W_hh, Wpk);
    embed_gemm<<<dim3(BATCH * SEQ / 128, HID / 128), 256, 0, stream>>>(
        X, emb, W_ih, b_ih, b_hh, buf);
    rnn_scan<<<BATCH, 512, 0, stream>>>(buf, Wpk);
    attn_ctx<<<BATCH, 256, 0, stream>>>(buf, feat);
    final_gemm<<<VOCAB / 64, 256, 0, stream>>>(W, bias, feat, out);
}

// Round 2
// 1053.747 us; speedup vs baseline: 1.1231x; 1.0188x over previous
//
#include <hip/hip_runtime.h>
#include <hip/hip_fp16.h>
#include <stdint.h>

#define VOCAB 32000
#define EMB   256
#define HID   512
#define BATCH 64
#define SEQ   512

// ---------------------------------------------------------------------------
// fp16 dot2: v_dot2_f32_f16 (2 MACs/lane/instr, fp32 accumulate)
// ---------------------------------------------------------------------------
typedef _Float16 h2_t __attribute__((ext_vector_type(2)));

__device__ __forceinline__ float fdot2(unsigned int a, unsigned int b, float c) {
#if __has_builtin(__builtin_amdgcn_fdot2)
    return __builtin_amdgcn_fdot2(__builtin_bit_cast(h2_t, a),
                                  __builtin_bit_cast(h2_t, b), c, false);
#else
    __half2 ah = __builtin_bit_cast(__half2, a);
    __half2 bh = __builtin_bit_cast(__half2, b);
    float2 af = __half22float2(ah), bf = __half22float2(bh);
    return fmaf(af.y, bf.y, fmaf(af.x, bf.x, c));
#endif
}

// DPP quad_perm lane-swap + add (pure VALU cross-lane within a hw quad)
template<int CTRL>
__device__ __forceinline__ float quad_add(float x) {
    int v = __builtin_amdgcn_update_dpp(0, __builtin_bit_cast(int, x),
                                        CTRL, 0xF, 0xF, true);
    return x + __builtin_bit_cast(float, v);
}
__device__ __forceinline__ float quad_reduce(float x) {
    x = quad_add<0xB1>(x);   // quad_perm [1,0,3,2] : xor 1
    x = quad_add<0x4E>(x);   // quad_perm [2,3,0,1] : xor 2
    return x;
}

// ---------------------------------------------------------------------------
// Kernel 1: pack W_hh (fp32 [r][k]) -> fp16 pairs, Wpk[j][r], j = k/2
// ---------------------------------------------------------------------------
__global__ void prep_whh(const float* __restrict__ W_hh, unsigned int* __restrict__ Wpk) {
    int idx = blockIdx.x * blockDim.x + threadIdx.x;      // = j*HID + r
    if (idx >= HID * (HID / 2)) return;
    int r = idx & (HID - 1);
    int j = idx >> 9;
    float lo = W_hh[r * HID + 2 * j];
    float hi = W_hh[r * HID + 2 * j + 1];
    unsigned int u = ((unsigned int)__half_as_ushort(__float2half(hi)) << 16)
                   |  (unsigned int)__half_as_ushort(__float2half(lo));
    Wpk[idx] = u;
}

// ---------------------------------------------------------------------------
// Kernel 2: xin[b][s][h] = emb[X[b][s]] . W_ih[h] + b_ih[h] + b_hh[h]  (fp16 out)
// 128x128 tile, BK=32, 256 thr, 8x8 acc/thread (split 4+4 to keep LDS 2-way free)
// ---------------------------------------------------------------------------
#define TSA 132

__global__ __launch_bounds__(256) void embed_gemm(
    const int* __restrict__ X, const float* __restrict__ emb,
    const float* __restrict__ W_ih, const float* __restrict__ b_ih,
    const float* __restrict__ b_hh, __half* __restrict__ xin) {
    __shared__ float A_l[32 * TSA];
    __shared__ float B_l[32 * TSA];
    const int tid = threadIdx.x;
    const int tx = tid & 15, ty = tid >> 4;
    const int sb0 = blockIdx.x * 128;   // (b*S+s) row tile
    const int h0  = blockIdx.y * 128;   // hidden col tile

    float acc[8][8] = {};   // rows {ty*4+i, 64+ty*4+i} x cols {tx*4+j, 64+tx*4+j}

    for (int kc = 0; kc < EMB; kc += 32) {
#pragma unroll
        for (int q = 0; q < 4; ++q) {
            int idx = q * 256 + tid;
            int r  = idx >> 3;          // 0..127
            int c4 = idx & 7;           // 0..7 float4 along k
            int row = X[sb0 + r];
            float4 v = *(const float4*)(emb + (size_t)row * EMB + kc + c4 * 4);
            A_l[(c4 * 4 + 0) * TSA + r] = v.x;
            A_l[(c4 * 4 + 1) * TSA + r] = v.y;
            A_l[(c4 * 4 + 2) * TSA + r] = v.z;
            A_l[(c4 * 4 + 3) * TSA + r] = v.w;
        }
#pragma unroll
        for (int q = 0; q < 4; ++q) {
            int idx = q * 256 + tid;
            int r  = idx >> 3;
            int c4 = idx & 7;
            float4 v = *(const float4*)(W_ih + (size_t)(h0 + r) * EMB + kc + c4 * 4);
            B_l[(c4 * 4 + 0) * TSA + r] = v.x;
            B_l[(c4 * 4 + 1) * TSA + r] = v.y;
            B_l[(c4 * 4 + 2) * TSA + r] = v.z;
            B_l[(c4 * 4 + 3) * TSA + r] = v.w;
        }
        __syncthreads();
#pragma unroll
        for (int k = 0; k < 32; ++k) {
            float4 a0 = *(const float4*)&A_l[k * TSA + ty * 4];
            float4 a1 = *(const float4*)&A_l[k * TSA + 64 + ty * 4];
            float4 b0 = *(const float4*)&B_l[k * TSA + tx * 4];
            float4 b1 = *(const float4*)&B_l[k * TSA + 64 + tx * 4];
            float ar[8] = {a0.x, a0.y, a0.z, a0.w, a1.x, a1.y, a1.z, a1.w};
            float br[8] = {b0.x, b0.y, b0.z, b0.w, b1.x, b1.y, b1.z, b1.w};
#pragma unroll
            for (int i = 0; i < 8; ++i)
#pragma unroll
                for (int j = 0; j < 8; ++j)
                    acc[i][j] = fmaf(ar[i], br[j], acc[i][j]);
        }
        __syncthreads();
    }

    float bias[8];
#pragma unroll
    for (int j = 0; j < 8; ++j) {
        int h = h0 + (j < 4 ? tx * 4 + j : 64 + tx * 4 + (j - 4));
        bias[j] = b_ih[h] + b_hh[h];
    }
#pragma unroll
    for (int i = 0; i < 8; ++i) {
        int r = sb0 + (i < 4 ? ty * 4 + i : 64 + ty * 4 + (i - 4));
        __half* dst = xin + (size_t)r * HID + h0;
        __half2 v01 = __floats2half2_rn(acc[i][0] + bias[0], acc[i][1] + bias[1]);
        __half2 v23 = __floats2half2_rn(acc[i][2] + bias[2], acc[i][3] + bias[3]);
        __half2 v45 = __floats2half2_rn(acc[i][4] + bias[4], acc[i][5] + bias[5]);
        __half2 v67 = __floats2half2_rn(acc[i][6] + bias[6], acc[i][7] + bias[7]);
        *(__half2*)(dst + tx * 4)          = v01;
        *(__half2*)(dst + tx * 4 + 2)      = v23;
        *(__half2*)(dst + 64 + tx * 4)     = v45;
        *(__half2*)(dst + 64 + tx * 4 + 2) = v67;
    }
}

// ---------------------------------------------------------------------------
// Kernel 3: sequential RNN scan, one 512-thread block per batch chain.
// Thread t (p=t>>2, g=t&3) owns rows {p+128i} over k-quarter g:
//   4 rows x 56 pairs in VGPRs (224) + 4 x 8 tail pairs in LDS (b128-readable).
// REGISTER BUDGET (round-2 fix): gfx950 unified file = 512 slots/lane/SIMD.
// With 8-wave blocks (2 waves/SIMD) the default heuristic allocated
// 128 VGPR + 128 AGPR per wave; wreg (224 dw) spilled to AGPRs -> ~200
// v_accvgpr_read copies per thread PER STEP (measured: VGPR_Count=128 both
// rounds, VALUBusy(active) ~72% vs ~30% dot2 floor). launch_bounds(512,1) is
// unsatisfiable (a 512-thr block is 2 waves/SIMD) and was ignored. The exact
// knob is amdgpu_waves_per_eu(2,2): budget = 512/2 = 256 arch VGPRs/wave,
// demand ~254 -> weights become direct v_dot2 operands, zero copies.
// wt stride 36 dwords (== +4 mod 32): consecutive 8 lanes' b128 reads tile all
// 32 banks exactly once -> conflict-free.
// h kept fp16 in LDS, double-buffered, quarters padded 16B (bank-disjoint
// 4-address multicast). DPP quad reduction -> 1 barrier/step.
// xin fp16 is overwritten in place with h (prefetch-before-write, thread-private).
// ---------------------------------------------------------------------------
#define QSTRIDE 272            // bytes per padded h quarter (256 data + 16 pad)
#define HBUF_DW 272            // dwords per h buffer = 4*272/4
#define NREG    56             // weight pairs per row kept in VGPRs
#define NTAIL   8              // weight pairs per row kept in LDS
#define WT_STR  36             // dwords per thread in wt (8 pairs x 4 rows + 4 pad)

__global__
__attribute__((amdgpu_flat_work_group_size(512, 512), amdgpu_waves_per_eu(2, 2)))
void rnn_scan(
    __half* __restrict__ buf,                     // [B][S][HID] fp16: xin in, h out
    const unsigned int* __restrict__ Wpk) {
    __shared__ unsigned int wt[WT_STR * 512];     // wt[t*WT_STR + k*4 + i]
    __shared__ unsigned int hbuf[2 * HBUF_DW];    // 2 x (4 padded quarters)

    const int t = threadIdx.x;
    const int b = blockIdx.x;
    const int g = t & 3;
    const int p = t >> 2;

    unsigned int wreg[4 * NREG];
#pragma unroll
    for (int i = 0; i < 4; ++i)
#pragma unroll
        for (int off = 0; off < NREG; ++off)
            wreg[i * NREG + off] = Wpk[(g * 64 + off) * HID + p + 128 * i];
#pragma unroll
    for (int k = 0; k < NTAIL; ++k)
#pragma unroll
        for (int i = 0; i < 4; ++i)
            wt[t * WT_STR + k * 4 + i] = Wpk[(g * 64 + NREG + k) * HID + p + 128 * i];
    for (int i = t; i < 2 * HBUF_DW; i += 512) hbuf[i] = 0;
    __syncthreads();

    const int rf = p + 128 * g;                   // row this thread finalizes
    const __half* xp = buf + (size_t)b * SEQ * HID + rf;
    __half* op = buf + (size_t)b * SEQ * HID + rf;
    const uint4* wt4 = (const uint4*)&wt[t * WT_STR];

    float xcur = __half2float(xp[0]);
    __half hprev = __float2half(0.0f);

    for (int s = 0; s < SEQ; ++s) {
        if (s > 0) op[(size_t)(s - 1) * HID] = hprev;     // last step's h, early
        float xnext = 0.0f;
        if (s + 1 < SEQ) xnext = __half2float(xp[(size_t)(s + 1) * HID]);

        const uint4* hq = (const uint4*)((const char*)hbuf
                              + (s & 1) * (HBUF_DW * 4) + g * QSTRIDE);
        float acc[4] = {0.f, 0.f, 0.f, 0.f};
#pragma unroll
        for (int q = 0; q < 14; ++q) {            // pairs 0..55 from VGPR weights
            uint4 h4 = hq[q];
#pragma unroll
            for (int i = 0; i < 4; ++i) {
                const unsigned int* wi = &wreg[i * NREG + 4 * q];
                acc[i] = fdot2(wi[0], h4.x, acc[i]);
                acc[i] = fdot2(wi[1], h4.y, acc[i]);
                acc[i] = fdot2(wi[2], h4.z, acc[i]);
                acc[i] = fdot2(wi[3], h4.w, acc[i]);
            }
        }
        {   // tail: pairs 56..63 from LDS (per-thread-contiguous b128, stride 36)
            uint4 h14 = hq[14];
            uint4 h15 = hq[15];
            unsigned int hc[NTAIL] = {h14.x, h14.y, h14.z, h14.w,
                                      h15.x, h15.y, h15.z, h15.w};
#pragma unroll
            for (int k = 0; k < NTAIL; ++k) {
                uint4 w = wt4[k];
                acc[0] = fdot2(w.x, hc[k], acc[0]);
                acc[1] = fdot2(w.y, hc[k], acc[1]);
                acc[2] = fdot2(w.z, hc[k], acc[2]);
                acc[3] = fdot2(w.w, hc[k], acc[3]);
            }
        }
        // reduce each row-partial over the quad (pure VALU), pick own row
        acc[0] = quad_reduce(acc[0]);
        acc[1] = quad_reduce(acc[1]);
        acc[2] = quad_reduce(acc[2]);
        acc[3] = quad_reduce(acc[3]);
        float dot = (g & 2) ? ((g & 1) ? acc[3] : acc[2])
                            : ((g & 1) ? acc[1] : acc[0]);
        float z = xcur + dot;
        float e = __expf(2.0f * z);                // tanh via exp, saturates right
        float hn = 1.0f - 2.0f / (e + 1.0f);
        __half hh = __float2half(hn);
        *((__half*)((char*)hbuf + ((s + 1) & 1) * (HBUF_DW * 4) + g * QSTRIDE) + p) = hh;
        hprev = hh;
        xcur = xnext;
        __syncthreads();                           // single barrier per step
    }
    op[(size_t)(SEQ - 1) * HID] = hprev;
}

// ---------------------------------------------------------------------------
// Kernel 4: attention over trajectory + feat assembly. One block per batch.
// ---------------------------------------------------------------------------
__global__ __launch_bounds__(256) void attn_ctx(
    const __half* __restrict__ h_all, float* __restrict__ feat) {
    const int b = blockIdx.x, tid = threadIdx.x;
    __shared__ float lastv[HID];
    __shared__ float sc[SEQ];
    __shared__ float red[256];
    const __half* hb = h_all + (size_t)b * SEQ * HID;

    for (int i = tid; i < HID; i += 256)
        lastv[i] = __half2float(hb[(size_t)(SEQ - 1) * HID + i]);
    __syncthreads();

    for (int s = tid; s < SEQ - 1; s += 256) {
        const __half* row = hb + (size_t)s * HID;
        float acc = 0.f;
        for (int r = 0; r < HID; r += 2) {
            __half2 hv = *(const __half2*)(row + r);
            float2 f = __half22float2(hv);
            acc = fmaf(f.x, lastv[r], acc);
            acc = fmaf(f.y, lastv[r + 1], acc);
        }
        sc[s] = acc;
    }
    __syncthreads();

    float m = -1e30f;
    for (int s = tid; s < SEQ - 1; s += 256) m = fmaxf(m, sc[s]);
    red[tid] = m;
    __syncthreads();
    for (int o = 128; o > 0; o >>= 1) {
        if (tid < o) red[tid] = fmaxf(red[tid], red[tid + o]);
        __syncthreads();
    }
    m = red[0];
    __syncthreads();

    float psum = 0.f;
    for (int s = tid; s < SEQ - 1; s += 256) {
        float e = expf(sc[s] - m);
        sc[s] = e;
        psum += e;
    }
    red[tid] = psum;
    __syncthreads();
    for (int o = 128; o > 0; o >>= 1) {
        if (tid < o) red[tid] += red[tid + o];
        __syncthreads();
    }
    float inv = 1.0f / red[0];
    __syncthreads();

    // ctx: each thread owns 2 adjacent r via half2, s-loop unrolled x4
    for (int r2 = tid; r2 < HID / 2; r2 += 256) {
        int r = r2 * 2;
        float accx = 0.f, accy = 0.f;
        int s = 0;
        for (; s + 4 <= SEQ - 1; s += 4) {
#pragma unroll
            for (int u = 0; u < 4; ++u) {
                __half2 hv = *(const __half2*)(hb + (size_t)(s + u) * HID + r);
                float2 f = __half22float2(hv);
                float w = sc[s + u];
                accx = fmaf(w, f.x, accx);
                accy = fmaf(w, f.y, accy);
            }
        }
        for (; s < SEQ - 1; ++s) {
            __half2 hv = *(const __half2*)(hb + (size_t)s * HID + r);
            float2 f = __half22float2(hv);
            float w = sc[s];
            accx = fmaf(w, f.x, accx);
            accy = fmaf(w, f.y, accy);
        }
        feat[(size_t)b * 2 * HID + r]     = accx * inv;
        feat[(size_t)b * 2 * HID + r + 1] = accy * inv;
        feat[(size_t)b * 2 * HID + HID + r]     = lastv[r];
        feat[(size_t)b * 2 * HID + HID + r + 1] = lastv[r + 1];
    }
}

// ---------------------------------------------------------------------------
// Kernel 5: out[b][v] = feat[b] . W[v] + bias[v].  64 v-rows x 64 b per block.
// ---------------------------------------------------------------------------
#define TS 68

__global__ __launch_bounds__(256) void final_gemm(
    const float* __restrict__ W, const float* __restrict__ bias,
    const float* __restrict__ feat, float* __restrict__ out) {
    __shared__ float A_l[64 * TS];   // W tile, k-major
    __shared__ float B_l[64 * TS];   // feat tile, k-major
    const int tid = threadIdx.x;
    const int tx = tid & 15, ty = tid >> 4;
    const int v0 = blockIdx.x * 64;

    float acc[4][4] = {};            // [v-row i][b-col ii]

    for (int kc = 0; kc < 2 * HID; kc += 64) {
#pragma unroll
        for (int q = 0; q < 4; ++q) {
            int idx = q * 256 + tid;
            int r  = idx >> 4;
            int c4 = idx & 15;
            const float4 v = *(const float4*)(W + (size_t)(v0 + r) * (2 * HID) + kc + c4 * 4);
            A_l[(c4 * 4 + 0) * TS + r] = v.x;
            A_l[(c4 * 4 + 1) * TS + r] = v.y;
            A_l[(c4 * 4 + 2) * TS + r] = v.z;
            A_l[(c4 * 4 + 3) * TS + r] = v.w;
        }
#pragma unroll
        for (int q = 0; q < 4; ++q) {
            int idx = q * 256 + tid;
            int r  = idx >> 4;       // batch row 0..63
            int c4 = idx & 15;
            const float4 v = *(const float4*)(feat + (size_t)r * (2 * HID) + kc + c4 * 4);
            B_l[(c4 * 4 + 0) * TS + r] = v.x;
            B_l[(c4 * 4 + 1) * TS + r] = v.y;
            B_l[(c4 * 4 + 2) * TS + r] = v.z;
            B_l[(c4 * 4 + 3) * TS + r] = v.w;
        }
        __syncthreads();
#pragma unroll 8
        for (int k = 0; k < 64; ++k) {
            float4 av = *(const float4*)&A_l[k * TS + ty * 4];
            float4 bv = *(const float4*)&B_l[k * TS + tx * 4];
            float a[4] = {av.x, av.y, av.z, av.w};
            float bb[4] = {bv.x, bv.y, bv.z, bv.w};
#pragma unroll
            for (int i = 0; i < 4; ++i)
#pragma unroll
                for (int ii = 0; ii < 4; ++ii)
                    acc[i][ii] = fmaf(a[i], bb[ii], acc[i][ii]);
        }
        __syncthreads();
    }

    float bs[4];
#pragma unroll
    for (int i = 0; i < 4; ++i) bs[i] = bias[v0 + ty * 4 + i];
#pragma unroll
    for (int ii = 0; ii < 4; ++ii) {
        int bb = tx * 4 + ii;
        float4 o;
        o.x = acc[0][ii] + bs[0];
        o.y = acc[1][ii] + bs[1];
        o.z = acc[2][ii] + bs[2];
        o.w = acc[3][ii] + bs[3];
        *(float4*)(out + (size_t)bb * VOCAB + v0 + ty * 4) = o;
    }
}

// ---------------------------------------------------------------------------
extern "C" void kernel_launch(void* const* d_in, const int* in_sizes, int n_in,
                              void* d_out, int out_size, void* d_ws, size_t ws_size,
                              hipStream_t stream) {
    const int*   X    = (const int*)d_in[0];
    const float* emb  = (const float*)d_in[1];
    const float* W_ih = (const float*)d_in[2];
    const float* W_hh = (const float*)d_in[3];
    const float* b_ih = (const float*)d_in[4];
    const float* b_hh = (const float*)d_in[5];
    const float* W    = (const float*)d_in[6];
    const float* bias = (const float*)d_in[7];
    float* out = (float*)d_out;

    // workspace: buf (xin fp16, overlaid with h) 32 MB | Wpk 512 KB | feat 256 KB
    const size_t BUF_B  = (size_t)BATCH * SEQ * HID * sizeof(__half);  // 33554432
    const size_t WPK_B  = (size_t)(HID * HID / 2) * sizeof(unsigned);  //   524288
    const size_t FEAT_B = (size_t)BATCH * 2 * HID * sizeof(float);     //   262144
    if (ws_size < BUF_B + WPK_B + FEAT_B) return;  // fail clean, don't corrupt

    char* ws = (char*)d_ws;
    __half*       buf  = (__half*)ws;
    unsigned int* Wpk  = (unsigned int*)(ws + BUF_B);
    float*        feat = (float*)(ws + BUF_B + WPK_B);

    prep_whh<<<(HID * HID / 2 + 255) / 256, 256, 0, stream>>>(W_hh, Wpk);
    embed_gemm<<<dim3(BATCH * SEQ / 128, HID / 128), 256, 0, stream>>>(
        X, emb, W_ih, b_ih, b_hh, buf);
    rnn_scan<<<BATCH, 512, 0, stream>>>(buf, Wpk);
    attn_ctx<<<BATCH, 256, 0, stream>>>(buf, feat);
    final_gemm<<<VOCAB / 64, 256, 0, stream>>>(W, bias, feat, out);
}